// Round 2
// baseline (239.943 us; speedup 1.0000x reference)
//
#include <hip/hip_runtime.h>
#include <hip/hip_bf16.h>

// Problem constants
#define NN  50000   // nodes
#define FD  128     // features
#define NE  800000  // external edges
#define NEI 400000  // internal edges
#define NG  64      // graphs

// Workspace layout (bytes). [0, ZERO_BYTES) is zeroed each launch.
#define DEG_EXT_OFF 0        // 50000 int
#define DEG_INT_OFF 200704   // 50000 int
#define EZ_OFF      401408   // 64*128 float
#define IZ_OFF      434176   // 64*128 float
#define CNT_OFF     466944   // 64 int
#define ZERO_BYTES  467200
#define WB_OFF      467200   // 4 convs * 32768 ushort = 256 KB (B fragments)
#define WCOL_OFF    729344   // 4 * 128 float

typedef short  short8 __attribute__((ext_vector_type(8)));
typedef float  f32x4  __attribute__((ext_vector_type(4)));

union S8 { short8 s; unsigned int u[4]; };

__device__ __forceinline__ unsigned short bf16h(float f) {
  unsigned int u = __float_as_uint(f);
  u += 0x7FFFu + ((u >> 16) & 1u);            // RNE
  return (unsigned short)(u >> 16);
}
__device__ __forceinline__ float bf16tof(unsigned short h) {
  return __uint_as_float(((unsigned int)h) << 16);
}
// packed 2xf32 -> 2xbf16 (v_cvt_pk_bf16_f32): a in low 16, b in high 16
__device__ __forceinline__ unsigned int pk_bf16(float a, float b) {
  __hip_bfloat162 h = __float22bfloat162_rn(make_float2(a, b));
  unsigned int u;
  __builtin_memcpy(&u, &h, 4);
  return u;
}
// fast reciprocal: v_rcp_f32 (~1 ulp) — tolerance is 4.2e-5, plenty of slack
__device__ __forceinline__ float frcp(float x) { return __builtin_amdgcn_rcpf(x); }

// -------------------------------------------------------------------------
// ONE aux dispatch (unchanged — all pieces measured small):
//  [0,391):    ext edge-degree histogram (softmax([E,1])==1 -> counts)
//  [391,587):  int edge-degree histogram
//  [587,600):  batch histogram (sorted -> LDS-privatized)
//  [600,608):  W -> MFMA B-fragment prep (hi/lo split-bf16), LDS-staged
// -------------------------------------------------------------------------
#define AB_EXT 391
#define AB_INT 196
#define AB_BAT 13
#define AB_PRE 8

__global__ __launch_bounds__(256) void aux_kernel(
    const int4* __restrict__ ei4, const int4* __restrict__ iei4,
    const int* __restrict__ batch,
    const float* __restrict__ wu_e1, const float* __restrict__ wu_e2,
    const float* __restrict__ wu_i1, const float* __restrict__ wu_i2,
    int* __restrict__ deg_ext, int* __restrict__ deg_int, int* __restrict__ cnt,
    unsigned short* __restrict__ WB, float* __restrict__ wcolp)
{
  __shared__ float WS[64 * 129];
  __shared__ int   hb[64];
  const int b = blockIdx.x, t = threadIdx.x;

  if (b < AB_EXT) {
    const int base = b * 512 + t;
    #pragma unroll
    for (int u = 0; u < 2; ++u) {
      const int i = base + u * 256;
      if (i < NE / 4) {
        const int4 v = ei4[i];
        atomicAdd(&deg_ext[v.x], 1);
        atomicAdd(&deg_ext[v.y], 1);
        atomicAdd(&deg_ext[v.z], 1);
        atomicAdd(&deg_ext[v.w], 1);
      }
    }
  } else if (b < AB_EXT + AB_INT) {
    const int base = (b - AB_EXT) * 512 + t;
    #pragma unroll
    for (int u = 0; u < 2; ++u) {
      const int i = base + u * 256;
      if (i < NEI / 4) {
        const int4 v = iei4[i];
        atomicAdd(&deg_int[v.x], 1);
        atomicAdd(&deg_int[v.y], 1);
        atomicAdd(&deg_int[v.z], 1);
        atomicAdd(&deg_int[v.w], 1);
      }
    }
  } else if (b < AB_EXT + AB_INT + AB_BAT) {
    if (t < 64) hb[t] = 0;
    __syncthreads();
    const int base = (b - AB_EXT - AB_INT) * 4096 + t;
    for (int u = 0; u < 16; ++u) {
      const int i = base + u * 256;
      if (i < NN) atomicAdd(&hb[batch[i]], 1);
    }
    __syncthreads();
    if (t < 64 && hb[t]) atomicAdd(&cnt[t], hb[t]);
  } else {
    const int pb = b - AB_EXT - AB_INT - AB_BAT;   // 0..7
    const int c  = pb >> 1;                         // conv 0..3
    const int h  = pb & 1;                          // row half
    const float* wu = (c == 0) ? wu_e1 : (c == 1) ? wu_e2 : (c == 2) ? wu_i1 : wu_i2;
    for (int idx = t; idx < 64 * 129; idx += 256)
      WS[idx] = wu[(size_t)h * 64 * 129 + idx];
    __syncthreads();
    const int lane = t & 63, u = t >> 6;
    const int n = lane & 15, quad = lane >> 4;
    const int ct = 4 * h + u;
    unsigned short* wb = WB + c * 32768;
    #pragma unroll
    for (int kc = 0; kc < 4; ++kc) {
      const int k0 = kc * 32 + quad * 8;
      const float* src = &WS[(u * 16 + n) * 129 + k0];
      short8 hi, lo;
      #pragma unroll
      for (int e = 0; e < 8; ++e) {
        const float v = src[e];
        const unsigned short hh = bf16h(v);
        hi[e] = (short)hh;
        lo[e] = (short)bf16h(v - bf16tof(hh));
      }
      const int fbase = ((ct * 4 + kc) * 2) * 512 + lane * 8;
      *(short8*)&wb[fbase]       = hi;
      *(short8*)&wb[fbase + 512] = lo;
    }
    if (t < 64) wcolp[c * 128 + h * 64 + t] = WS[t * 129 + 128];
  }
}

// -------------------------------------------------------------------------
// Fused conv chain — MERGED-CHAIN rewrite (R10).
// One block = 64 nodes x BOTH chains (ext+int): grid 1564 -> 782.
//  * x staged once; conv1-ext/int share each ds_read A-fragment (1 read
//    feeds 4 MFMAs).
//  * s1 computed as exact f32 cross-wave reduction (drops ONES-MFMA).
//  * all divisions -> v_rcp_f32; row inverses computed ONCE per row
//    (lane ℓ owns row ℓ) and broadcast via __shfl — removes ~450
//    redundant VALU/thread vs R9.
//  * XT ping-pong: x->XT0; E1e->XT1 (after b2: XT0 reads provably done);
//    E1i->XT0; conv2e reads XT1; b3; conv2i reads XT0.  redA/redB carry
//    s1 partials (written pre-b2, read pre-b3) then s2 partials (written
//    post-b3, read post-b4).  4 barriers for both chains (was 3 + 3).
// LDS 36.8 KB.  VGPR target <=128 (launch_bounds 512,4).
// -------------------------------------------------------------------------
__global__ __launch_bounds__(512, 4) void conv_mfma_kernel(
    const float* __restrict__ x,
    const int* __restrict__ deg_ext, const int* __restrict__ deg_int,
    const int* __restrict__ batch,
    const unsigned short* __restrict__ WB, const float* __restrict__ wcolp,
    const float* __restrict__ bu_e1, const float* __restrict__ bu_e2,
    const float* __restrict__ bu_i1, const float* __restrict__ bu_i2,
    float* __restrict__ ez_sum, float* __restrict__ iz_sum)
{
  __shared__ unsigned short XT[2][8192];   // A fragments (bf16), 2 x 16 KB
  __shared__ float degsE[64];
  __shared__ float degsI[64];
  __shared__ int   bg[64];
  __shared__ float redA[64 * 8];           // [row][wave]: s1e, then s2e
  __shared__ float redB[64 * 8];           // [row][wave]: s1i, then s2i

  const int tid  = threadIdx.x;
  const int lane = tid & 63;
  const int w    = tid >> 6;        // wave = column tile 0..7
  const int n    = lane & 15;
  const int q    = lane >> 4;
  const int mbase = blockIdx.x * 64;
  const int j = w * 16 + n;         // this lane's output column

#define LOADB(CONV, BH, BL) do {                                              \
    const unsigned short* _p = WB + (CONV) * 32768 + (w * 4) * 1024 + lane * 8;\
    _Pragma("unroll")                                                          \
    for (int _kc = 0; _kc < 4; ++_kc) {                                        \
      BH[_kc] = *(const short8*)&_p[_kc * 1024];                               \
      BL[_kc] = *(const short8*)&_p[_kc * 1024 + 512];                         \
    }                                                                          \
  } while (0)

  // ---- hoist conv1 B-slices (both chains) + per-column scalars
  short8 BEh[4], BEl[4], BIh[4], BIl[4];
  LOADB(0, BEh, BEl);               // ext conv1
  LOADB(2, BIh, BIl);               // int conv1
  const float wcE1 = wcolp[0 * 128 + j], wcE2 = wcolp[1 * 128 + j];
  const float wcI1 = wcolp[2 * 128 + j], wcI2 = wcolp[3 * 128 + j];
  const float bE1 = bu_e1[j], bE2 = bu_e2[j];
  const float bI1 = bu_i1[j], bI2 = bu_i2[j];

  // ---- stage x -> bf16 A fragments in XT[0], octet-linear (conflict-free)
  #pragma unroll
  for (int u = 0; u < 2; ++u) {
    const int oct  = u * 512 + tid;          // 1024 octets
    const int frag = oct >> 6, l = oct & 63;
    const int row  = (frag >> 2) * 16 + (l & 15);
    const int k0   = (frag & 3) * 32 + (l >> 4) * 8;
    const int node = mbase + row;
    float4 a = make_float4(0.f, 0.f, 0.f, 0.f), bb = a;
    if (node < NN) {
      const float* xr = x + (size_t)node * FD + k0;
      a  = *(const float4*)xr;
      bb = *(const float4*)(xr + 4);
    }
    S8 hi;
    hi.u[0] = pk_bf16(a.x, a.y);
    hi.u[1] = pk_bf16(a.z, a.w);
    hi.u[2] = pk_bf16(bb.x, bb.y);
    hi.u[3] = pk_bf16(bb.z, bb.w);
    *(short8*)&XT[0][oct * 8] = hi.s;
  }
  if (tid < 64) {
    const int node = mbase + tid;
    const bool v = node < NN;
    degsE[tid] = v ? (float)deg_ext[node] : 0.f;
    degsI[tid] = v ? (float)deg_int[node] : 0.f;
    bg[tid]    = v ? batch[node] : 0;
  }
  __syncthreads();   // ---- barrier 1: A fragments + degs + bg visible

  // ================= conv1, both chains share each A read ================
  f32x4 aE[4], aI[4];
  #pragma unroll
  for (int rt = 0; rt < 4; ++rt) {
    aE[rt] = (f32x4){0.f, 0.f, 0.f, 0.f};
    aI[rt] = (f32x4){0.f, 0.f, 0.f, 0.f};
  }
  #pragma unroll
  for (int kc = 0; kc < 4; ++kc) {
    #pragma unroll
    for (int rt = 0; rt < 4; ++rt) {
      const short8 Ah = *(const short8*)&XT[0][((rt * 4 + kc) * 64 + lane) * 8];
      f32x4 ce = aE[rt];
      ce = __builtin_amdgcn_mfma_f32_16x16x32_bf16(Ah, BEh[kc], ce, 0, 0, 0);
      ce = __builtin_amdgcn_mfma_f32_16x16x32_bf16(Ah, BEl[kc], ce, 0, 0, 0);
      aE[rt] = ce;
      f32x4 ci = aI[rt];
      ci = __builtin_amdgcn_mfma_f32_16x16x32_bf16(Ah, BIh[kc], ci, 0, 0, 0);
      ci = __builtin_amdgcn_mfma_f32_16x16x32_bf16(Ah, BIl[kc], ci, 0, 0, 0);
      aI[rt] = ci;
    }
  }

  // ---- epilogue1 (both chains): E1 = exp(leaky(acc + b + deg*wc)), f32
  #pragma unroll
  for (int rt = 0; rt < 4; ++rt) {
    const float4 dE = *(const float4*)&degsE[rt * 16 + 4 * q];
    const float4 dI = *(const float4*)&degsI[rt * 16 + 4 * q];
    const float dEv[4] = {dE.x, dE.y, dE.z, dE.w};
    const float dIv[4] = {dI.x, dI.y, dI.z, dI.w};
    #pragma unroll
    for (int r = 0; r < 4; ++r) {
      float ve = aE[rt][r] + bE1 + dEv[r] * wcE1;
      ve = fmaxf(ve, 0.01f * ve);
      aE[rt][r] = __expf(ve);
      float vi = aI[rt][r] + bI1 + dIv[r] * wcI1;
      vi = fmaxf(vi, 0.01f * vi);
      aI[rt][r] = __expf(vi);
    }
  }

  // ---- s1 partials (exact f32): row-sum over this wave's 16 cols
  #pragma unroll
  for (int rt = 0; rt < 4; ++rt) {
    #pragma unroll
    for (int r = 0; r < 4; ++r) {
      float te = aE[rt][r], ti = aI[rt][r];
      te += __shfl_xor(te, 1); ti += __shfl_xor(ti, 1);
      te += __shfl_xor(te, 2); ti += __shfl_xor(ti, 2);
      te += __shfl_xor(te, 4); ti += __shfl_xor(ti, 4);
      te += __shfl_xor(te, 8); ti += __shfl_xor(ti, 8);
      if (n == 0) {
        redA[(rt * 16 + q * 4 + r) * 8 + w] = te;
        redB[(rt * 16 + q * 4 + r) * 8 + w] = ti;
      }
    }
  }

  // ---- pack E1 to bf16 pairs (regs); reload B for conv2 (latency hides
  //      under the pack + barrier)
  unsigned int pE[4][2], pI[4][2];
  #pragma unroll
  for (int rt = 0; rt < 4; ++rt) {
    pE[rt][0] = pk_bf16(aE[rt][0], aE[rt][1]);
    pE[rt][1] = pk_bf16(aE[rt][2], aE[rt][3]);
    pI[rt][0] = pk_bf16(aI[rt][0], aI[rt][1]);
    pI[rt][1] = pk_bf16(aI[rt][2], aI[rt][3]);
  }
  LOADB(1, BEh, BEl);               // ext conv2 (reuses B regs)
  LOADB(3, BIh, BIl);               // int conv2

  // ---- write E1e -> XT[1] in A-fragment order (no WAR: XT[1] fresh)
  #pragma unroll
  for (int rt = 0; rt < 4; ++rt) {
    const int ib = ((rt * 4 + (w >> 1)) * 64 + ((w & 1) * 2 + (n >> 3)) * 16 + q * 4) * 8 + (n & 7);
    XT[1][ib]      = (unsigned short)(pE[rt][0] & 0xFFFFu);
    XT[1][ib + 8]  = (unsigned short)(pE[rt][0] >> 16);
    XT[1][ib + 16] = (unsigned short)(pE[rt][1] & 0xFFFFu);
    XT[1][ib + 24] = (unsigned short)(pE[rt][1] >> 16);
  }
  __syncthreads();   // ---- barrier 2: XT1 + s1 partials visible; XT0 reads done

  // ---- write E1i -> XT[0] (safe now)
  #pragma unroll
  for (int rt = 0; rt < 4; ++rt) {
    const int ib = ((rt * 4 + (w >> 1)) * 64 + ((w & 1) * 2 + (n >> 3)) * 16 + q * 4) * 8 + (n & 7);
    XT[0][ib]      = (unsigned short)(pI[rt][0] & 0xFFFFu);
    XT[0][ib + 8]  = (unsigned short)(pI[rt][0] >> 16);
    XT[0][ib + 16] = (unsigned short)(pI[rt][1] & 0xFFFFu);
    XT[0][ib + 24] = (unsigned short)(pI[rt][1] >> 16);
  }

  // ---- row-owned s1 inverses: lane ℓ sums row ℓ (1 rcp per row, not 16)
  float s1iE, s1iI;
  {
    const f32x4 a0 = *(const f32x4*)&redA[lane * 8];
    const f32x4 a1 = *(const f32x4*)&redA[lane * 8 + 4];
    s1iE = frcp(((a0[0] + a0[1]) + (a0[2] + a0[3])) + ((a1[0] + a1[1]) + (a1[2] + a1[3])));
    const f32x4 b0 = *(const f32x4*)&redB[lane * 8];
    const f32x4 b1 = *(const f32x4*)&redB[lane * 8 + 4];
    s1iI = frcp(((b0[0] + b0[1]) + (b0[2] + b0[3])) + ((b1[0] + b1[1]) + (b1[2] + b1[3])));
  }

  // ================= conv2-ext from XT[1] =================
  f32x4 cE[4], cI[4];
  #pragma unroll
  for (int rt = 0; rt < 4; ++rt) cE[rt] = (f32x4){0.f, 0.f, 0.f, 0.f};
  #pragma unroll
  for (int kc = 0; kc < 4; ++kc) {
    #pragma unroll
    for (int rt = 0; rt < 4; ++rt) {
      const short8 Ah = *(const short8*)&XT[1][((rt * 4 + kc) * 64 + lane) * 8];
      f32x4 c = cE[rt];
      c = __builtin_amdgcn_mfma_f32_16x16x32_bf16(Ah, BEh[kc], c, 0, 0, 0);
      c = __builtin_amdgcn_mfma_f32_16x16x32_bf16(Ah, BEl[kc], c, 0, 0, 0);
      cE[rt] = c;
    }
  }
  __syncthreads();   // ---- barrier 3: E1i visible; redA/redB s1-reads done

  // ================= conv2-int from XT[0] =================
  #pragma unroll
  for (int rt = 0; rt < 4; ++rt) cI[rt] = (f32x4){0.f, 0.f, 0.f, 0.f};
  #pragma unroll
  for (int kc = 0; kc < 4; ++kc) {
    #pragma unroll
    for (int rt = 0; rt < 4; ++rt) {
      const short8 Ah = *(const short8*)&XT[0][((rt * 4 + kc) * 64 + lane) * 8];
      f32x4 c = cI[rt];
      c = __builtin_amdgcn_mfma_f32_16x16x32_bf16(Ah, BIh[kc], c, 0, 0, 0);
      c = __builtin_amdgcn_mfma_f32_16x16x32_bf16(Ah, BIl[kc], c, 0, 0, 0);
      cI[rt] = c;
    }
  }

  // ---- epilogue2 (both chains): logits = U2*inv_s1 + b + deg*wc;
  //      E2 = exp(leaky(.)); s2 partials -> redA/redB (safe after b3)
  #pragma unroll
  for (int rt = 0; rt < 4; ++rt) {
    const float4 dE = *(const float4*)&degsE[rt * 16 + 4 * q];
    const float4 dI = *(const float4*)&degsI[rt * 16 + 4 * q];
    const float dEv[4] = {dE.x, dE.y, dE.z, dE.w};
    const float dIv[4] = {dI.x, dI.y, dI.z, dI.w};
    #pragma unroll
    for (int r = 0; r < 4; ++r) {
      const int row = rt * 16 + q * 4 + r;
      const float i1e = __shfl(s1iE, row);
      const float i1i = __shfl(s1iI, row);
      float ue = cE[rt][r] * i1e + bE2 + dEv[r] * wcE2;
      ue = fmaxf(ue, 0.01f * ue);
      cE[rt][r] = __expf(ue);
      float ui = cI[rt][r] * i1i + bI2 + dIv[r] * wcI2;
      ui = fmaxf(ui, 0.01f * ui);
      cI[rt][r] = __expf(ui);
    }
    #pragma unroll
    for (int r = 0; r < 4; ++r) {
      float te = cE[rt][r], ti = cI[rt][r];
      te += __shfl_xor(te, 1); ti += __shfl_xor(ti, 1);
      te += __shfl_xor(te, 2); ti += __shfl_xor(ti, 2);
      te += __shfl_xor(te, 4); ti += __shfl_xor(ti, 4);
      te += __shfl_xor(te, 8); ti += __shfl_xor(ti, 8);
      if (n == 0) {
        redA[(rt * 16 + q * 4 + r) * 8 + w] = te;
        redB[(rt * 16 + q * 4 + r) * 8 + w] = ti;
      }
    }
  }
  __syncthreads();   // ---- barrier 4: s2 partials visible

  // ---- row-owned s2 inverses + normalize
  float s2iE, s2iI;
  {
    const f32x4 a0 = *(const f32x4*)&redA[lane * 8];
    const f32x4 a1 = *(const f32x4*)&redA[lane * 8 + 4];
    s2iE = frcp(((a0[0] + a0[1]) + (a0[2] + a0[3])) + ((a1[0] + a1[1]) + (a1[2] + a1[3])));
    const f32x4 b0 = *(const f32x4*)&redB[lane * 8];
    const f32x4 b1 = *(const f32x4*)&redB[lane * 8 + 4];
    s2iI = frcp(((b0[0] + b0[1]) + (b0[2] + b0[3])) + ((b1[0] + b1[1]) + (b1[2] + b1[3])));
  }
  #pragma unroll
  for (int rt = 0; rt < 4; ++rt) {
    #pragma unroll
    for (int r = 0; r < 4; ++r) {
      const int row = rt * 16 + q * 4 + r;
      cE[rt][r] *= __shfl(s2iE, row);
      cI[rt][r] *= __shfl(s2iI, row);
    }
  }

  // ---- scatter into per-graph sums (batch sorted: one-graph fast path)
  {
    bool fast = false; int gall = 0;
    if (mbase + 63 < NN) { gall = bg[0]; fast = (bg[63] == gall); }
    if (fast) {
      float se = 0.f, si = 0.f;
      #pragma unroll
      for (int rt = 0; rt < 4; ++rt)
        #pragma unroll
        for (int r = 0; r < 4; ++r) { se += cE[rt][r]; si += cI[rt][r]; }
      se += __shfl_xor(se, 16); si += __shfl_xor(si, 16);
      se += __shfl_xor(se, 32); si += __shfl_xor(si, 32);
      if (q == 0) {
        atomicAdd(&ez_sum[gall * FD + j], se);
        atomicAdd(&iz_sum[gall * FD + j], si);
      }
    } else {
      #pragma unroll
      for (int rt = 0; rt < 4; ++rt)
        #pragma unroll
        for (int r = 0; r < 4; ++r) {
          const int row = rt * 16 + q * 4 + r;
          if (mbase + row < NN) {
            atomicAdd(&ez_sum[bg[row] * FD + j], cE[rt][r]);
            atomicAdd(&iz_sum[bg[row] * FD + j], cI[rt][r]);
          }
        }
    }
  }
#undef LOADB
}

// -------------------------------------------------------------------------
// Final MLP: 64 blocks (one per graph) x 128 threads.
// -------------------------------------------------------------------------
__global__ __launch_bounds__(128) void fc_kernel(
    const float* __restrict__ ez_sum, const float* __restrict__ iz_sum,
    const int* __restrict__ cnt,
    const float* __restrict__ fc1_w, const float* __restrict__ fc1_b,
    const float* __restrict__ fc2_w, const float* __restrict__ fc2_b,
    float* __restrict__ out)
{
  __shared__ float z[256];
  __shared__ float red2[2];
  const int g = blockIdx.x, t = threadIdx.x;
  const float denom = fmaxf((float)cnt[g], 1.0f);
  z[t]       = ez_sum[g * 128 + t] / denom;
  z[128 + t] = iz_sum[g * 128 + t] / denom;
  __syncthreads();

  const float* wr = fc1_w + (size_t)t * 256;
  float a = fc1_b[t];
  #pragma unroll 4
  for (int c = 0; c < 256; c += 4) {
    const float4 wv = *(const float4*)(wr + c);
    a += wv.x * z[c] + wv.y * z[c + 1] + wv.z * z[c + 2] + wv.w * z[c + 3];
  }
  a = fmaxf(a, 0.f) * fc2_w[t];
  a += __shfl_xor(a, 1);
  a += __shfl_xor(a, 2);
  a += __shfl_xor(a, 4);
  a += __shfl_xor(a, 8);
  a += __shfl_xor(a, 16);
  a += __shfl_xor(a, 32);
  if ((t & 63) == 0) red2[t >> 6] = a;
  __syncthreads();
  if (t == 0) out[g] = red2[0] + red2[1] + fc2_b[0];
}

// -------------------------------------------------------------------------
extern "C" void kernel_launch(void* const* d_in, const int* in_sizes, int n_in,
                              void* d_out, int out_size, void* d_ws, size_t ws_size,
                              hipStream_t stream) {
  const float* x     = (const float*)d_in[0];
  const int4*  ei4   = (const int4*) d_in[1];   // [2,E]: first E = sources
  const int4*  iei4  = (const int4*) d_in[3];
  const int*   batch = (const int*)  d_in[5];
  const float* wu_e1 = (const float*)d_in[8];
  const float* bu_e1 = (const float*)d_in[9];
  const float* wu_e2 = (const float*)d_in[12];
  const float* bu_e2 = (const float*)d_in[13];
  const float* wu_i1 = (const float*)d_in[16];
  const float* bu_i1 = (const float*)d_in[17];
  const float* wu_i2 = (const float*)d_in[20];
  const float* bu_i2 = (const float*)d_in[21];
  const float* fc1_w = (const float*)d_in[22];
  const float* fc1_b = (const float*)d_in[23];
  const float* fc2_w = (const float*)d_in[24];
  const float* fc2_b = (const float*)d_in[25];

  char* ws = (char*)d_ws;
  int*   deg_ext = (int*)  (ws + DEG_EXT_OFF);
  int*   deg_int = (int*)  (ws + DEG_INT_OFF);
  float* ez      = (float*)(ws + EZ_OFF);
  float* iz      = (float*)(ws + IZ_OFF);
  int*   cnt     = (int*)  (ws + CNT_OFF);
  unsigned short* WB = (unsigned short*)(ws + WB_OFF);
  float* wcolp   = (float*)(ws + WCOL_OFF);

  hipMemsetAsync(d_ws, 0, ZERO_BYTES, stream);

  aux_kernel<<<AB_EXT + AB_INT + AB_BAT + AB_PRE, 256, 0, stream>>>(
      ei4, iei4, batch, wu_e1, wu_e2, wu_i1, wu_i2,
      deg_ext, deg_int, cnt, WB, wcolp);

  conv_mfma_kernel<<<dim3((NN + 63) / 64), 512, 0, stream>>>(
      x, deg_ext, deg_int, batch, WB, wcolp,
      bu_e1, bu_e2, bu_i1, bu_i2, ez, iz);

  fc_kernel<<<NG, 128, 0, stream>>>(ez, iz, cnt, fc1_w, fc1_b, fc2_w, fc2_b,
                                    (float*)d_out);
}